// Round 10
// baseline (107.469 us; speedup 1.0000x reference)
//
#include <hip/hip_runtime.h>
#include <math.h>

#define LQ 512
#define NH 12
#define ND 384
#define PAIRC 128
#define RSQRT3 0.5773502691896258f
// sq scale: (1/4)*(1/sqrt(3))
#define SQSCALE 0.1443375672974065f
// point coef: 0.5/sqrt(18)/sqrt(3) = 0.5/sqrt(54)
#define PTCOEF 0.06804138174397717f

typedef __attribute__((ext_vector_type(8))) short short8v;
typedef __attribute__((ext_vector_type(4))) float f32x4;

__device__ __forceinline__ unsigned short f2bf(float f){
  unsigned int u = __float_as_uint(f);
  unsigned int r = (u + 0x7FFFu + ((u >> 16) & 1u)) >> 16;
  return (unsigned short)r;
}
__device__ __forceinline__ float bf2f(unsigned short u){
  return __uint_as_float(((unsigned int)u) << 16);
}
__device__ __forceinline__ void split2(float v, unsigned short* hi, unsigned short* lo){
  unsigned short h16 = f2bf(v);
  *hi = h16;
  *lo = f2bf(v - bf2f(h16));
}
__device__ __forceinline__ short8v pack8(float4 a, float4 b){
  short8v s;
  s[0]=(short)f2bf(a.x); s[1]=(short)f2bf(a.y); s[2]=(short)f2bf(a.z); s[3]=(short)f2bf(a.w);
  s[4]=(short)f2bf(b.x); s[5]=(short)f2bf(b.y); s[6]=(short)f2bf(b.z); s[7]=(short)f2bf(b.w);
  return s;
}

// ---------------------------------------------------------------------------
// K0: pack node + concatenated weights into bf16 hi/lo. (verified r5)
// ---------------------------------------------------------------------------
__global__ __launch_bounds__(256) void k0_pack(
    const float* __restrict__ node,
    const float* __restrict__ sq_k, const float* __restrict__ sk_k, const float* __restrict__ sv_k,
    const float* __restrict__ pq_k, const float* __restrict__ pk_k, const float* __restrict__ pv_k,
    unsigned short* __restrict__ nh, unsigned short* __restrict__ nl,
    unsigned short* __restrict__ Wh, unsigned short* __restrict__ Wl)
{
  int idx = blockIdx.x*256 + threadIdx.x;     // 0 .. 638975
  if (idx < 196608) {
    unsigned short hi, lo;
    split2(node[idx], &hi, &lo);
    nh[idx] = hi; nl[idx] = lo;
  } else {
    int widx = idx - 196608;                  // = (h*96+ch)*384 + k
    int h = widx / 36864;
    int rem = widx - h*36864;
    int ch = rem / 384;
    int k = rem - ch*384;
    float val;
    if (ch < 16)      val = sq_k[((size_t)h*ND + k)*16 + ch] * SQSCALE;
    else if (ch < 32) val = sk_k[((size_t)h*ND + k)*16 + ch - 16];
    else if (ch < 48) val = sv_k[((size_t)h*ND + k)*16 + ch - 32];
    else if (ch < 60) val = pq_k[((size_t)h*ND + k)*12 + ch - 48];
    else if (ch < 72) val = pk_k[((size_t)h*ND + k)*12 + ch - 60];
    else              val = pv_k[((size_t)h*ND + k)*24 + ch - 72];
    unsigned short hi, lo;
    split2(val, &hi, &lo);
    Wh[widx] = hi; Wl[widx] = lo;
  }
}

// ---------------------------------------------------------------------------
// K1: projection GEMM via hi/lo MFMA. (verified r5)
// ---------------------------------------------------------------------------
__global__ __launch_bounds__(64) void k1_mfma(
    const unsigned short* __restrict__ nh, const unsigned short* __restrict__ nl,
    const unsigned short* __restrict__ Wh, const unsigned short* __restrict__ Wl,
    float* __restrict__ proj)
{
  const int lt = blockIdx.x, h = blockIdx.y, kz = blockIdx.z;
  const int lane = threadIdx.x;
  const int lh = lane & 15, lg = lane >> 4;

  f32x4 acc[6];
  #pragma unroll
  for (int ms = 0; ms < 6; ++ms) { f32x4 z = {0.f,0.f,0.f,0.f}; acc[ms] = z; }

  const unsigned short* nrh = nh + ((size_t)lt*16 + lh)*384;
  const unsigned short* nrl = nl + ((size_t)lt*16 + lh)*384;
  #pragma unroll 2
  for (int ks = 0; ks < 6; ++ks) {
    const int koff = kz*192 + ks*32 + lg*8;
    short8v ah = *(const short8v*)(nrh + koff);
    short8v al = *(const short8v*)(nrl + koff);
    #pragma unroll
    for (int ms = 0; ms < 6; ++ms) {
      const size_t wo = ((size_t)h*96 + ms*16 + lh)*384 + koff;
      short8v bh = *(const short8v*)(Wh + wo);
      short8v bl = *(const short8v*)(Wl + wo);
      acc[ms] = __builtin_amdgcn_mfma_f32_16x16x32_bf16(ah, bh, acc[ms], 0, 0, 0);
      acc[ms] = __builtin_amdgcn_mfma_f32_16x16x32_bf16(ah, bl, acc[ms], 0, 0, 0);
      acc[ms] = __builtin_amdgcn_mfma_f32_16x16x32_bf16(al, bh, acc[ms], 0, 0, 0);
    }
  }
  float* dst = proj + (size_t)kz*589824 + ((size_t)h*LQ + lt*16)*96;
  #pragma unroll
  for (int ms = 0; ms < 6; ++ms) {
    #pragma unroll
    for (int r = 0; r < 4; ++r)
      dst[(lg*4 + r)*96 + ms*16 + lh] = acc[ms][r];
  }
}

// ---------------------------------------------------------------------------
// K1b: sum proj partials, rotate points, assemble hi/lo features. (verified r5)
// ---------------------------------------------------------------------------
__global__ __launch_bounds__(256) void k1b_feat(
    const float* __restrict__ proj, const float* __restrict__ Rm, const float* __restrict__ tv,
    const float* __restrict__ pwgt,
    unsigned short* __restrict__ qfh, unsigned short* __restrict__ qfl,
    unsigned short* __restrict__ kfh, unsigned short* __restrict__ kfl,
    unsigned short* __restrict__ vf_w)
{
  int idx = blockIdx.x*256 + threadIdx.x;   // 12*512
  int h = idx >> 9, l = idx & 511;
  float x = pwgt[h];
  float sp = (x > 20.f) ? x : log1pf(__expf(x));
  float cpw = sp * PTCOEF;

  float v[96];
  {
    const float4* a = (const float4*)(proj + ((size_t)h*LQ + l)*96);
    const float4* b = (const float4*)(proj + 589824 + ((size_t)h*LQ + l)*96);
    #pragma unroll
    for (int i = 0; i < 24; ++i) {
      float4 p = a[i], q = b[i];
      v[4*i+0] = p.x + q.x; v[4*i+1] = p.y + q.y;
      v[4*i+2] = p.z + q.z; v[4*i+3] = p.w + q.w;
    }
  }
  float R_[9], t_[3];
  #pragma unroll
  for (int q = 0; q < 9; ++q) R_[q] = Rm[(size_t)l*9 + q];
  #pragma unroll
  for (int q = 0; q < 3; ++q) t_[q] = tv[(size_t)l*3 + q];
  #pragma unroll
  for (int p = 0; p < 16; ++p) {
    float x0 = v[48+p*3], y0 = v[48+p*3+1], z0 = v[48+p*3+2];
    v[48+p*3+0] = x0*R_[0] + y0*R_[1] + z0*R_[2] + t_[0];
    v[48+p*3+1] = x0*R_[3] + y0*R_[4] + z0*R_[5] + t_[1];
    v[48+p*3+2] = x0*R_[6] + y0*R_[7] + z0*R_[8] + t_[2];
  }

  const size_t base = ((size_t)h*LQ + l)*32;
  float pkn = 0.f;
  #pragma unroll
  for (int j = 0; j < 12; ++j) { float w = v[60+j]; pkn += w*w; }
  #pragma unroll
  for (int j = 0; j < 16; ++j) {
    split2(v[j],    &qfh[base+j], &qfl[base+j]);
    split2(v[16+j], &kfh[base+j], &kfl[base+j]);
  }
  #pragma unroll
  for (int j = 0; j < 12; ++j) {
    split2(v[48+j]*(2.f*cpw), &qfh[base+16+j], &qfl[base+16+j]);
    split2(v[60+j],           &kfh[base+16+j], &kfl[base+16+j]);
  }
  split2(-cpw, &qfh[base+28], &qfl[base+28]);
  split2(pkn,  &kfh[base+28], &kfl[base+28]);
  #pragma unroll
  for (int j = 29; j < 32; ++j) {
    qfh[base+j]=0; qfl[base+j]=0; kfh[base+j]=0; kfl[base+j]=0;
  }

  #pragma unroll
  for (int vv = 0; vv < 48; ++vv) {
    float val = (vv < 16) ? v[32+vv] : (vv < 40 ? v[72+vv-16] : 0.f);
    vf_w[((size_t)h*48 + vv)*LQ + l] = f2bf(val);
  }
}

// ---------------------------------------------------------------------------
// K_qk: pre-logits via 3x MFMA hi/lo. pre[h][n][m] f32. (verified r5)
// ---------------------------------------------------------------------------
__global__ __launch_bounds__(256) void k_qk(
    const unsigned short* __restrict__ qfh, const unsigned short* __restrict__ qfl,
    const unsigned short* __restrict__ kfh, const unsigned short* __restrict__ kfl,
    float* __restrict__ pre_w)
{
  const int n0 = blockIdx.x*64, m0 = blockIdx.y*64, h = blockIdx.z;
  const int tid = threadIdx.x, lane = tid & 63, w = tid >> 6;
  const int lh = lane & 15, lg = lane >> 4;

  const size_t qoff = ((size_t)h*LQ + n0 + w*16 + lh)*32 + lg*8;
  short8v ah = *(const short8v*)(qfh + qoff);
  short8v al = *(const short8v*)(qfl + qoff);
  #pragma unroll
  for (int ms = 0; ms < 4; ++ms) {
    const size_t koff = ((size_t)h*LQ + m0 + ms*16 + lh)*32 + lg*8;
    short8v bh = *(const short8v*)(kfh + koff);
    short8v bl = *(const short8v*)(kfl + koff);
    f32x4 d = {0.f,0.f,0.f,0.f};
    d = __builtin_amdgcn_mfma_f32_16x16x32_bf16(ah, bh, d, 0, 0, 0);
    d = __builtin_amdgcn_mfma_f32_16x16x32_bf16(ah, bl, d, 0, 0, 0);
    d = __builtin_amdgcn_mfma_f32_16x16x32_bf16(al, bh, d, 0, 0, 0);
    #pragma unroll
    for (int r = 0; r < 4; ++r) {
      int nn = n0 + w*16 + lg*4 + r;
      pre_w[((size_t)h*LQ + nn)*LQ + m0 + ms*16 + lh] = d[r];
    }
  }
}

// ---------------------------------------------------------------------------
// K2I: fused pairwise logits + softmax + pairwise PV. One block per n,
// 1024 threads = 16 waves (4 waves/SIMD for latency hiding; r7/r9 had 2).
// Wave w owns m in [w*32, w*32+32) (2 f-iterations, both preloaded).
// fp8 pw tile [c=128][m=512] swizzled in LDS; PV split-K across wave pairs.
// LDS ~88KB -> 1 block/CU, 16 waves/CU.
// ---------------------------------------------------------------------------
#define PRE_STR 520
__global__ __launch_bounds__(1024, 4) void k2i_attn(
    const float* __restrict__ pw, const float* __restrict__ pr_k,
    const float* __restrict__ pre_w,
    unsigned short* __restrict__ attn_w, unsigned short* __restrict__ rh_w)
{
  const int n = blockIdx.x;
  const int tid = threadIdx.x, lane = tid & 63, w = tid >> 6;   // w: 0..15
  const int lh = lane & 15, lg = lane >> 4;

  __shared__ __align__(16) char smem[12480 + 65536];
  __shared__ float red[2][16][16];
  __shared__ float pvred[8][16][16];
  unsigned short* plds = (unsigned short*)smem;   // [12][520] bf16
  char* pwlds = smem + 12480;                     // [128][512] fp8, swizzled

  // pr B-frags (constant): B[k=c][col=h]
  short8v prf[4];
  #pragma unroll
  for (int ks = 0; ks < 4; ++ks) {
    short8v s = {0,0,0,0,0,0,0,0};
    if (lh < 12) {
      const float* p = pr_k + (size_t)lh*PAIRC + ks*32 + lg*8;
      #pragma unroll
      for (int j = 0; j < 8; ++j) s[j] = (short)f2bf(p[j] * RSQRT3);
    }
    prf[ks] = s;
  }

  // ---- phase 1: stream pw rows (2 f-iters, fully preloaded) ----
  const int mbase = w * 32;
  const float* rowp = pw + (size_t)n*LQ*PAIRC + (size_t)(mbase + lh)*PAIRC;

  float4 buf0[8], buf1[8];
  #pragma unroll
  for (int q = 0; q < 8; ++q)
    buf0[q] = *(const float4*)(rowp + (q>>1)*32 + lg*8 + (q&1)*4);
  #pragma unroll
  for (int q = 0; q < 8; ++q)
    buf1[q] = *(const float4*)(rowp + 16*PAIRC + (q>>1)*32 + lg*8 + (q&1)*4);

  f32x4 acc[2];
  { f32x4 z = {0.f,0.f,0.f,0.f}; acc[0] = z; acc[1] = z; }

  {
    const int m = mbase + lh;
    const int mrow = m >> 3, mbyte = m & 7;
    #pragma unroll
    for (int ks = 0; ks < 4; ++ks) {
      float4 A = buf0[ks*2], B = buf0[ks*2+1];
      short8v a = pack8(A, B);
      acc[0] = __builtin_amdgcn_mfma_f32_16x16x32_bf16(a, prf[ks], acc[0], 0, 0, 0);
      int u0 = __builtin_amdgcn_cvt_pk_fp8_f32(A.x, A.y, 0, false);
      u0 = __builtin_amdgcn_cvt_pk_fp8_f32(A.z, A.w, u0, true);
      int u1 = __builtin_amdgcn_cvt_pk_fp8_f32(B.x, B.y, 0, false);
      u1 = __builtin_amdgcn_cvt_pk_fp8_f32(B.z, B.w, u1, true);
      #pragma unroll
      for (int j = 0; j < 8; ++j) {
        const int c = ks*32 + lg*8 + j;
        const int slot = mrow ^ ((c & 7) << 3) ^ ((c >> 3) & 7);
        pwlds[(size_t)c*512 + (slot << 3) + mbyte] =
            (char)(((j < 4 ? u0 : u1) >> (8*(j & 3))) & 0xff);
      }
    }
  }
  {
    const int m = mbase + 16 + lh;
    const int mrow = m >> 3, mbyte = m & 7;
    #pragma unroll
    for (int ks = 0; ks < 4; ++ks) {
      float4 A = buf1[ks*2], B = buf1[ks*2+1];
      short8v a = pack8(A, B);
      acc[1] = __builtin_amdgcn_mfma_f32_16x16x32_bf16(a, prf[ks], acc[1], 0, 0, 0);
      int u0 = __builtin_amdgcn_cvt_pk_fp8_f32(A.x, A.y, 0, false);
      u0 = __builtin_amdgcn_cvt_pk_fp8_f32(A.z, A.w, u0, true);
      int u1 = __builtin_amdgcn_cvt_pk_fp8_f32(B.x, B.y, 0, false);
      u1 = __builtin_amdgcn_cvt_pk_fp8_f32(B.z, B.w, u1, true);
      #pragma unroll
      for (int j = 0; j < 8; ++j) {
        const int c = ks*32 + lg*8 + j;
        const int slot = mrow ^ ((c & 7) << 3) ^ ((c >> 3) & 7);
        pwlds[(size_t)c*512 + (slot << 3) + mbyte] =
            (char)(((j < 4 ? u0 : u1) >> (8*(j & 3))) & 0xff);
      }
    }
  }

  // pre -> registers (after phase 1 to keep peak VGPR low)
  float4 pre4[2];
  #pragma unroll
  for (int f = 0; f < 2; ++f) {
    if (lh < 12)
      pre4[f] = *(const float4*)(pre_w + ((size_t)lh*LQ + n)*LQ + mbase + f*16 + lg*4);
    else { float4 z = {0.f,0.f,0.f,0.f}; pre4[f] = z; }
  }

  // ---- logits + block softmax (head = lh, m = mbase + f*16 + lg*4 + r) ----
  float mx = -INFINITY;
  #pragma unroll
  for (int f = 0; f < 2; ++f) {
    #pragma unroll
    for (int r = 0; r < 4; ++r) {
      float p = (r == 0) ? pre4[f].x : (r == 1) ? pre4[f].y : (r == 2) ? pre4[f].z : pre4[f].w;
      float v = acc[f][r] + p;
      acc[f][r] = v;
      mx = fmaxf(mx, v);
    }
  }
  mx = fmaxf(mx, __shfl_xor(mx, 16));
  mx = fmaxf(mx, __shfl_xor(mx, 32));
  if (lane < 16) red[0][w][lane] = mx;
  __syncthreads();   // B2
  float M = red[0][0][lh];
  #pragma unroll
  for (int w2 = 1; w2 < 16; ++w2) M = fmaxf(M, red[0][w2][lh]);
  float sm = 0.f;
  #pragma unroll
  for (int f = 0; f < 2; ++f) {
    #pragma unroll
    for (int r = 0; r < 4; ++r) {
      float e = __expf(acc[f][r] - M);
      acc[f][r] = e;
      sm += e;
    }
  }
  sm += __shfl_xor(sm, 16);
  sm += __shfl_xor(sm, 32);
  if (lane < 16) red[1][w][lane] = sm;
  __syncthreads();   // B3
  float S = red[1][0][lh];
  #pragma unroll
  for (int w2 = 1; w2 < 16; ++w2) S += red[1][w2][lh];
  float rinv = 1.f / S;
  if (lh < 12) {
    #pragma unroll
    for (int f = 0; f < 2; ++f) {
      #pragma unroll
      for (int r = 0; r < 4; ++r) {
        int m = mbase + f*16 + lg*4 + r;
        plds[lh*PRE_STR + m] = f2bf(acc[f][r] * rinv);
      }
    }
  }
  __syncthreads();   // B4: plds + pwlds ready

  // attn global write (bf16) for K5
  if (tid < 768) {
    int h = tid >> 6, m = (tid & 63) * 8;
    short8v v = *(const short8v*)(plds + h*PRE_STR + m);
    *(short8v*)(attn_w + ((size_t)h*LQ + n)*LQ + m) = v;
  }

  // ---- phase 2: PV via fp8 MFMA, split-K across wave pairs ----
  // wave w: c-block cb = w & 7 (c = cb*16 + lh), K-half kh = w >> 3.
  const int cb = w & 7, kh = w >> 3;
  const int c = cb*16 + lh;

  long a_r[8];
  #pragma unroll
  for (int ks8 = 0; ks8 < 8; ++ks8) {
    const int ks = kh*8 + ks8;
    const unsigned short* ap = plds + lh*PRE_STR + ks*32 + lg*8;
    float f0 = bf2f(ap[0]), f1 = bf2f(ap[1]), f2 = bf2f(ap[2]), f3 = bf2f(ap[3]);
    float f4 = bf2f(ap[4]), f5 = bf2f(ap[5]), f6 = bf2f(ap[6]), f7 = bf2f(ap[7]);
    int u0 = __builtin_amdgcn_cvt_pk_fp8_f32(f0, f1, 0, false);
    u0 = __builtin_amdgcn_cvt_pk_fp8_f32(f2, f3, u0, true);
    int u1 = __builtin_amdgcn_cvt_pk_fp8_f32(f4, f5, 0, false);
    u1 = __builtin_amdgcn_cvt_pk_fp8_f32(f6, f7, u1, true);
    a_r[ks8] = (long)((((unsigned long long)(unsigned)u1) << 32) | (unsigned)u0);
  }
  f32x4 o = {0.f,0.f,0.f,0.f};
  #pragma unroll
  for (int ks8 = 0; ks8 < 8; ++ks8) {
    const int ks = kh*8 + ks8;
    const int slot = (ks*4 + lg) ^ ((c & 7) << 3) ^ ((c >> 3) & 7);
    long b = *(const long*)(pwlds + (size_t)c*512 + (slot << 3));
    o = __builtin_amdgcn_mfma_f32_16x16x32_fp8_fp8(a_r[ks8], b, o, 0, 0, 0);
  }
  if (kh == 1) {
    #pragma unroll
    for (int r = 0; r < 4; ++r) pvred[cb][lg*4 + r][lh] = o[r];
  }
  __syncthreads();   // B5: partials visible
  if (kh == 0) {
    #pragma unroll
    for (int r = 0; r < 4; ++r) {
      int h = lg*4 + r;
      if (h < 12) {
        float val = o[r] + pvred[cb][lg*4 + r][lh];
        rh_w[(size_t)n*2112 + h*176 + 16 + c] = f2bf(val);
      }
    }
  }
}

// ---------------------------------------------------------------------------
// K5: scaler + point PV from materialized attn, with fused point-output
// frame transform + norms via an LDS stage. (verified r8)
// ---------------------------------------------------------------------------
__global__ __launch_bounds__(256) void k5_svpv(
    const unsigned short* __restrict__ attn_w, const unsigned short* __restrict__ vf_w,
    const float* __restrict__ Rm, const float* __restrict__ tv,
    unsigned short* __restrict__ rh_w)
{
  const int n0 = blockIdx.x*64, h = blockIdx.y;
  const int tid = threadIdx.x, lane = tid & 63, w = tid >> 6;
  const int lh = lane & 15, lg = lane >> 4;
  const int nb = n0 + w*16;

  __shared__ float po_s[64][24];

  f32x4 acc[3];
  #pragma unroll
  for (int v = 0; v < 3; ++v) { f32x4 z = {0.f,0.f,0.f,0.f}; acc[v] = z; }

  #pragma unroll 4
  for (int ks = 0; ks < 16; ++ks) {
    short8v a = *(const short8v*)(attn_w + ((size_t)h*LQ + nb + lh)*LQ + ks*32 + lg*8);
    #pragma unroll
    for (int v = 0; v < 3; ++v) {
      short8v b = *(const short8v*)(vf_w + ((size_t)h*48 + v*16 + lh)*LQ + ks*32 + lg*8);
      acc[v] = __builtin_amdgcn_mfma_f32_16x16x32_bf16(a, b, acc[v], 0, 0, 0);
    }
  }
  #pragma unroll
  for (int v = 0; v < 3; ++v) {
    #pragma unroll
    for (int r = 0; r < 4; ++r) {
      int col = v*16 + lh;
      int nn = nb + lg*4 + r;
      float val = acc[v][r];
      if (col < 16)      rh_w[(size_t)nn*2112 + h*176 + col] = f2bf(val);
      else if (col < 40) po_s[nn - n0][col - 16] = val;
    }
  }
  __syncthreads();
  // point transform: subtract t, rotate by R^T, norms
  #pragma unroll
  for (int it = 0; it < 2; ++it) {
    int slot = it*256 + tid;          // 0..511
    int nl = slot >> 3, p = slot & 7;
    int nn = n0 + nl;
    float v0 = po_s[nl][p*3+0] - tv[(size_t)nn*3+0];
    float v1 = po_s[nl][p*3+1] - tv[(size_t)nn*3+1];
    float v2 = po_s[nl][p*3+2] - tv[(size_t)nn*3+2];
    const float* R_ = Rm + (size_t)nn*9;
    float f0 = v0*R_[0] + v1*R_[3] + v2*R_[6];
    float f1 = v0*R_[1] + v1*R_[4] + v2*R_[7];
    float f2 = v0*R_[2] + v1*R_[5] + v2*R_[8];
    unsigned short* d = rh_w + (size_t)nn*2112 + h*176;
    d[144 + p*3 + 0] = f2bf(f0);
    d[144 + p*3 + 1] = f2bf(f1);
    d[144 + p*3 + 2] = f2bf(f2);
    d[168 + p] = f2bf(sqrtf(f0*f0 + f1*f1 + f2*f2 + 1e-12f));
  }
}

// ---------------------------------------------------------------------------
// K3packB: out_k [2112][384] f32 -> bh_t [384][2112] bf16 (LDS tile transpose)
// ---------------------------------------------------------------------------
__global__ __launch_bounds__(256) void k3_packB(
    const float* __restrict__ out_k, unsigned short* __restrict__ bh_t)
{
  const int i0 = blockIdx.x*64, o0 = blockIdx.y*64;
  const int tid = threadIdx.x;
  __shared__ float t[64][65];
  #pragma unroll
  for (int e = 0; e < 16; ++e) {
    int idx = e*256 + tid;
    int i = idx >> 6, o = idx & 63;
    t[i][o] = out_k[(size_t)(i0 + i)*384 + o0 + o];
  }
  __syncthreads();
  #pragma unroll
  for (int e = 0; e < 16; ++e) {
    int idx = e*256 + tid;
    int o = idx >> 6, i = idx & 63;
    bh_t[(size_t)(o0 + o)*2112 + i0 + i] = f2bf(t[i][o]);
  }
}

// ---------------------------------------------------------------------------
// K3: out = res(512x2112, bf16) @ out_k^T(384x2112, bf16) via MFMA, split-K 6.
// ---------------------------------------------------------------------------
__global__ __launch_bounds__(256) void k3_mfma(
    const unsigned short* __restrict__ rh, const unsigned short* __restrict__ bh_t,
    float* __restrict__ part)
{
  const int l0 = blockIdx.x*64, o0 = blockIdx.y*64, z = blockIdx.z;
  const int tid = threadIdx.x, lane = tid & 63, w = tid >> 6;
  const int lh = lane & 15, lg = lane >> 4;
  const int wr = w >> 1, wc = w & 1;

  f32x4 acc[2][2];
  #pragma unroll
  for (int t = 0; t < 2; ++t)
    #pragma unroll
    for (int u = 0; u < 2; ++u) { f32x4 zz = {0.f,0.f,0.f,0.f}; acc[t][u] = zz; }

  const int k0 = z*352;
  #pragma unroll 2
  for (int ks = 0; ks < 11; ++ks) {
    const int koff = k0 + ks*32 + lg*8;
    short8v at[2], bt[2];
    #pragma unroll
    for (int t = 0; t < 2; ++t)
      at[t] = *(const short8v*)(rh + (size_t)(l0 + wr*32 + t*16 + lh)*2112 + koff);
    #pragma unroll
    for (int u = 0; u < 2; ++u)
      bt[u] = *(const short8v*)(bh_t + (size_t)(o0 + wc*32 + u*16 + lh)*2112 + koff);
    #pragma unroll
    for (int t = 0; t < 2; ++t)
      #pragma unroll
      for (int u = 0; u < 2; ++u)
        acc[t][u] = __builtin_amdgcn_mfma_f32_16x16x32_bf16(at[t], bt[u], acc[t][u], 0, 0, 0);
  }
  #pragma unroll
  for (int t = 0; t < 2; ++t)
    #pragma unroll
    for (int u = 0; u < 2; ++u)
      #pragma unroll
      for (int r = 0; r < 4; ++r) {
        int l = l0 + wr*32 + t*16 + lg*4 + r;
        int o = o0 + wc*32 + u*16 + lh;
        part[((size_t)z*LQ + l)*384 + o] = acc[t][u][r];
      }
}

__global__ __launch_bounds__(256) void k3_red(
    const float* __restrict__ part, const float* __restrict__ bias, float* __restrict__ out)
{
  int e4 = blockIdx.x*256 + threadIdx.x;   // 0..49151
  const float4* P4 = (const float4*)part;
  float4 s = {0,0,0,0};
  #pragma unroll
  for (int z = 0; z < 6; ++z) {
    float4 v = P4[(size_t)z*49152 + e4];
    s.x += v.x; s.y += v.y; s.z += v.z; s.w += v.w;
  }
  float4 b = ((const float4*)bias)[e4 % 96];
  s.x += b.x; s.y += b.y; s.z += b.z; s.w += b.w;
  ((float4*)out)[e4] = s;
}

// ---------------------------------------------------------------------------
extern "C" void kernel_launch(void* const* d_in, const int* in_sizes, int n_in,
                              void* d_out, int out_size, void* d_ws, size_t ws_size,
                              hipStream_t stream) {
  (void)in_sizes; (void)n_in; (void)out_size; (void)ws_size;
  const float* node  = (const float*)d_in[0];
  const float* Rm    = (const float*)d_in[1];
  const float* tv    = (const float*)d_in[2];
  const float* pairw = (const float*)d_in[3];
  const float* sq_k  = (const float*)d_in[4];
  const float* sk_k  = (const float*)d_in[5];
  const float* sv_k  = (const float*)d_in[6];
  const float* pq_k  = (const float*)d_in[7];
  const float* pk_k  = (const float*)d_in[8];
  const float* pv_k  = (const float*)d_in[9];
  const float* pr_k  = (const float*)d_in[10];
  const float* out_k = (const float*)d_in[11];
  const float* out_b = (const float*)d_in[12];
  const float* pwgt  = (const float*)d_in[13];

  float* ws = (float*)d_ws;
  // pre_w spans [0, 3145728); k1-stage scratch + k3 partials alias inside it.
  float* pre_w = ws + 0;                                   // 3145728 f
  unsigned short* nh   = (unsigned short*)(ws + 0);
  unsigned short* nl   = (unsigned short*)(ws + 98304);
  unsigned short* Wh   = (unsigned short*)(ws + 196608);
  unsigned short* Wl   = (unsigned short*)(ws + 417792);
  float* proj = ws + 638976;                               // 2 x 589824 f
  float* part_w = ws + 0;                                  // 1179648 f (alias pre)
  unsigned short* qfh = (unsigned short*)(ws + 3145728);
  unsigned short* qfl = (unsigned short*)(ws + 3244032);
  unsigned short* kfh = (unsigned short*)(ws + 3342336);
  unsigned short* kfl = (unsigned short*)(ws + 3440640);
  unsigned short* vf_w = (unsigned short*)(ws + 3538944);  // 294912 sh
  unsigned short* attn_w = (unsigned short*)(ws + 3686400);// 3145728 sh
  unsigned short* rh_w = (unsigned short*)(ws + 5259264);  // 1081344 sh
  unsigned short* bh_t = (unsigned short*)(ws + 5947392);  // 811008 sh

  k0_pack<<<dim3(2496,1,1), 256, 0, stream>>>(node, sq_k, sk_k, sv_k, pq_k, pk_k, pv_k,
                                              nh, nl, Wh, Wl);
  k1_mfma<<<dim3(32,12,2), 64, 0, stream>>>(nh, nl, Wh, Wl, proj);
  k1b_feat<<<dim3(24,1,1), 256, 0, stream>>>(proj, Rm, tv, pwgt,
                                             qfh, qfl, kfh, kfl, vf_w);
  k_qk<<<dim3(8,8,12), 256, 0, stream>>>(qfh, qfl, kfh, kfl, pre_w);
  k2i_attn<<<dim3(512,1,1), 1024, 0, stream>>>(pairw, pr_k, pre_w, attn_w, rh_w);
  k5_svpv<<<dim3(8,12,1), 256, 0, stream>>>(attn_w, vf_w, Rm, tv, rh_w);
  k3_packB<<<dim3(33,6,1), 256, 0, stream>>>(out_k, bh_t);
  k3_mfma<<<dim3(8,6,6), 256, 0, stream>>>(rh_w, bh_t, part_w);
  k3_red<<<dim3(192,1,1), 256, 0, stream>>>(part_w, out_b, (float*)d_out);
}

// Round 11
// 100.883 us; speedup vs baseline: 1.0653x; 1.0653x over previous
//
#include <hip/hip_runtime.h>
#include <math.h>

#define LQ 512
#define NH 12
#define ND 384
#define PAIRC 128
#define RSQRT3 0.5773502691896258f
// sq scale: (1/4)*(1/sqrt(3))
#define SQSCALE 0.1443375672974065f
// point coef: 0.5/sqrt(18)/sqrt(3) = 0.5/sqrt(54)
#define PTCOEF 0.06804138174397717f

typedef __attribute__((ext_vector_type(8))) short short8v;
typedef __attribute__((ext_vector_type(4))) float f32x4;

__device__ __forceinline__ unsigned short f2bf(float f){
  unsigned int u = __float_as_uint(f);
  unsigned int r = (u + 0x7FFFu + ((u >> 16) & 1u)) >> 16;
  return (unsigned short)r;
}
__device__ __forceinline__ float bf2f(unsigned short u){
  return __uint_as_float(((unsigned int)u) << 16);
}
__device__ __forceinline__ void split2(float v, unsigned short* hi, unsigned short* lo){
  unsigned short h16 = f2bf(v);
  *hi = h16;
  *lo = f2bf(v - bf2f(h16));
}
__device__ __forceinline__ short8v pack8(float4 a, float4 b){
  short8v s;
  s[0]=(short)f2bf(a.x); s[1]=(short)f2bf(a.y); s[2]=(short)f2bf(a.z); s[3]=(short)f2bf(a.w);
  s[4]=(short)f2bf(b.x); s[5]=(short)f2bf(b.y); s[6]=(short)f2bf(b.z); s[7]=(short)f2bf(b.w);
  return s;
}
// truncating pack (1 op/elem); used for the high-volume prd A-operand only.
__device__ __forceinline__ short8v pack8t(float4 a, float4 b){
  short8v s;
  s[0]=(short)(__float_as_uint(a.x)>>16); s[1]=(short)(__float_as_uint(a.y)>>16);
  s[2]=(short)(__float_as_uint(a.z)>>16); s[3]=(short)(__float_as_uint(a.w)>>16);
  s[4]=(short)(__float_as_uint(b.x)>>16); s[5]=(short)(__float_as_uint(b.y)>>16);
  s[6]=(short)(__float_as_uint(b.z)>>16); s[7]=(short)(__float_as_uint(b.w)>>16);
  return s;
}

// ---------------------------------------------------------------------------
// K0: pack node + concatenated weights into bf16 hi/lo. (verified r5)
// ---------------------------------------------------------------------------
__global__ __launch_bounds__(256) void k0_pack(
    const float* __restrict__ node,
    const float* __restrict__ sq_k, const float* __restrict__ sk_k, const float* __restrict__ sv_k,
    const float* __restrict__ pq_k, const float* __restrict__ pk_k, const float* __restrict__ pv_k,
    unsigned short* __restrict__ nh, unsigned short* __restrict__ nl,
    unsigned short* __restrict__ Wh, unsigned short* __restrict__ Wl)
{
  int idx = blockIdx.x*256 + threadIdx.x;     // 0 .. 638975
  if (idx < 196608) {
    unsigned short hi, lo;
    split2(node[idx], &hi, &lo);
    nh[idx] = hi; nl[idx] = lo;
  } else {
    int widx = idx - 196608;                  // = (h*96+ch)*384 + k
    int h = widx / 36864;
    int rem = widx - h*36864;
    int ch = rem / 384;
    int k = rem - ch*384;
    float val;
    if (ch < 16)      val = sq_k[((size_t)h*ND + k)*16 + ch] * SQSCALE;
    else if (ch < 32) val = sk_k[((size_t)h*ND + k)*16 + ch - 16];
    else if (ch < 48) val = sv_k[((size_t)h*ND + k)*16 + ch - 32];
    else if (ch < 60) val = pq_k[((size_t)h*ND + k)*12 + ch - 48];
    else if (ch < 72) val = pk_k[((size_t)h*ND + k)*12 + ch - 60];
    else              val = pv_k[((size_t)h*ND + k)*24 + ch - 72];
    unsigned short hi, lo;
    split2(val, &hi, &lo);
    Wh[widx] = hi; Wl[widx] = lo;
  }
}

// ---------------------------------------------------------------------------
// K1: projection GEMM via hi/lo MFMA. (verified r5)
// ---------------------------------------------------------------------------
__global__ __launch_bounds__(64) void k1_mfma(
    const unsigned short* __restrict__ nh, const unsigned short* __restrict__ nl,
    const unsigned short* __restrict__ Wh, const unsigned short* __restrict__ Wl,
    float* __restrict__ proj)
{
  const int lt = blockIdx.x, h = blockIdx.y, kz = blockIdx.z;
  const int lane = threadIdx.x;
  const int lh = lane & 15, lg = lane >> 4;

  f32x4 acc[6];
  #pragma unroll
  for (int ms = 0; ms < 6; ++ms) { f32x4 z = {0.f,0.f,0.f,0.f}; acc[ms] = z; }

  const unsigned short* nrh = nh + ((size_t)lt*16 + lh)*384;
  const unsigned short* nrl = nl + ((size_t)lt*16 + lh)*384;
  #pragma unroll 2
  for (int ks = 0; ks < 6; ++ks) {
    const int koff = kz*192 + ks*32 + lg*8;
    short8v ah = *(const short8v*)(nrh + koff);
    short8v al = *(const short8v*)(nrl + koff);
    #pragma unroll
    for (int ms = 0; ms < 6; ++ms) {
      const size_t wo = ((size_t)h*96 + ms*16 + lh)*384 + koff;
      short8v bh = *(const short8v*)(Wh + wo);
      short8v bl = *(const short8v*)(Wl + wo);
      acc[ms] = __builtin_amdgcn_mfma_f32_16x16x32_bf16(ah, bh, acc[ms], 0, 0, 0);
      acc[ms] = __builtin_amdgcn_mfma_f32_16x16x32_bf16(ah, bl, acc[ms], 0, 0, 0);
      acc[ms] = __builtin_amdgcn_mfma_f32_16x16x32_bf16(al, bh, acc[ms], 0, 0, 0);
    }
  }
  float* dst = proj + (size_t)kz*589824 + ((size_t)h*LQ + lt*16)*96;
  #pragma unroll
  for (int ms = 0; ms < 6; ++ms) {
    #pragma unroll
    for (int r = 0; r < 4; ++r)
      dst[(lg*4 + r)*96 + ms*16 + lh] = acc[ms][r];
  }
}

// ---------------------------------------------------------------------------
// K1b: sum proj partials, rotate points, assemble hi/lo features. (verified r5)
// ---------------------------------------------------------------------------
__global__ __launch_bounds__(256) void k1b_feat(
    const float* __restrict__ proj, const float* __restrict__ Rm, const float* __restrict__ tv,
    const float* __restrict__ pwgt,
    unsigned short* __restrict__ qfh, unsigned short* __restrict__ qfl,
    unsigned short* __restrict__ kfh, unsigned short* __restrict__ kfl,
    unsigned short* __restrict__ vf_w)
{
  int idx = blockIdx.x*256 + threadIdx.x;   // 12*512
  int h = idx >> 9, l = idx & 511;
  float x = pwgt[h];
  float sp = (x > 20.f) ? x : log1pf(__expf(x));
  float cpw = sp * PTCOEF;

  float v[96];
  {
    const float4* a = (const float4*)(proj + ((size_t)h*LQ + l)*96);
    const float4* b = (const float4*)(proj + 589824 + ((size_t)h*LQ + l)*96);
    #pragma unroll
    for (int i = 0; i < 24; ++i) {
      float4 p = a[i], q = b[i];
      v[4*i+0] = p.x + q.x; v[4*i+1] = p.y + q.y;
      v[4*i+2] = p.z + q.z; v[4*i+3] = p.w + q.w;
    }
  }
  float R_[9], t_[3];
  #pragma unroll
  for (int q = 0; q < 9; ++q) R_[q] = Rm[(size_t)l*9 + q];
  #pragma unroll
  for (int q = 0; q < 3; ++q) t_[q] = tv[(size_t)l*3 + q];
  #pragma unroll
  for (int p = 0; p < 16; ++p) {
    float x0 = v[48+p*3], y0 = v[48+p*3+1], z0 = v[48+p*3+2];
    v[48+p*3+0] = x0*R_[0] + y0*R_[1] + z0*R_[2] + t_[0];
    v[48+p*3+1] = x0*R_[3] + y0*R_[4] + z0*R_[5] + t_[1];
    v[48+p*3+2] = x0*R_[6] + y0*R_[7] + z0*R_[8] + t_[2];
  }

  const size_t base = ((size_t)h*LQ + l)*32;
  float pkn = 0.f;
  #pragma unroll
  for (int j = 0; j < 12; ++j) { float w = v[60+j]; pkn += w*w; }
  #pragma unroll
  for (int j = 0; j < 16; ++j) {
    split2(v[j],    &qfh[base+j], &qfl[base+j]);
    split2(v[16+j], &kfh[base+j], &kfl[base+j]);
  }
  #pragma unroll
  for (int j = 0; j < 12; ++j) {
    split2(v[48+j]*(2.f*cpw), &qfh[base+16+j], &qfl[base+16+j]);
    split2(v[60+j],           &kfh[base+16+j], &kfl[base+16+j]);
  }
  split2(-cpw, &qfh[base+28], &qfl[base+28]);
  split2(pkn,  &kfh[base+28], &kfl[base+28]);
  #pragma unroll
  for (int j = 29; j < 32; ++j) {
    qfh[base+j]=0; qfl[base+j]=0; kfh[base+j]=0; kfl[base+j]=0;
  }

  #pragma unroll
  for (int vv = 0; vv < 48; ++vv) {
    float val = (vv < 16) ? v[32+vv] : (vv < 40 ? v[72+vv-16] : 0.f);
    vf_w[((size_t)h*48 + vv)*LQ + l] = f2bf(val);
  }
}

// ---------------------------------------------------------------------------
// K_qk: pre-logits via 3x MFMA hi/lo. pre[h][n][m] f32. (verified r5)
// ---------------------------------------------------------------------------
__global__ __launch_bounds__(256) void k_qk(
    const unsigned short* __restrict__ qfh, const unsigned short* __restrict__ qfl,
    const unsigned short* __restrict__ kfh, const unsigned short* __restrict__ kfl,
    float* __restrict__ pre_w)
{
  const int n0 = blockIdx.x*64, m0 = blockIdx.y*64, h = blockIdx.z;
  const int tid = threadIdx.x, lane = tid & 63, w = tid >> 6;
  const int lh = lane & 15, lg = lane >> 4;

  const size_t qoff = ((size_t)h*LQ + n0 + w*16 + lh)*32 + lg*8;
  short8v ah = *(const short8v*)(qfh + qoff);
  short8v al = *(const short8v*)(qfl + qoff);
  #pragma unroll
  for (int ms = 0; ms < 4; ++ms) {
    const size_t koff = ((size_t)h*LQ + m0 + ms*16 + lh)*32 + lg*8;
    short8v bh = *(const short8v*)(kfh + koff);
    short8v bl = *(const short8v*)(kfl + koff);
    f32x4 d = {0.f,0.f,0.f,0.f};
    d = __builtin_amdgcn_mfma_f32_16x16x32_bf16(ah, bh, d, 0, 0, 0);
    d = __builtin_amdgcn_mfma_f32_16x16x32_bf16(ah, bl, d, 0, 0, 0);
    d = __builtin_amdgcn_mfma_f32_16x16x32_bf16(al, bh, d, 0, 0, 0);
    #pragma unroll
    for (int r = 0; r < 4; ++r) {
      int nn = n0 + w*16 + lg*4 + r;
      pre_w[((size_t)h*LQ + nn)*LQ + m0 + ms*16 + lh] = d[r];
    }
  }
}

// ---------------------------------------------------------------------------
// K2J: fused pairwise logits + softmax + pairwise PV. One block per n.
// r7 structure, but __launch_bounds__(256,2) grants a 256-VGPR budget so the
// 2-deep register pipeline actually lives in registers (r6's profile showed
// VGPR_Count=64 with ~130 live => the compiler was spilling the pipeline to
// scratch; this is the fix under test). trunc-pack for the prd A-operand;
// pre staged to registers AFTER phase 1 (lower peak pressure).
// LDS ~77KB -> 2 blocks/CU.
// ---------------------------------------------------------------------------
#define PRE_STR 520
__global__ __launch_bounds__(256, 2) void k2j_attn(
    const float* __restrict__ pw, const float* __restrict__ pr_k,
    const float* __restrict__ pre_w,
    unsigned short* __restrict__ attn_w, unsigned short* __restrict__ rh_w)
{
  const int n = blockIdx.x;
  const int tid = threadIdx.x, lane = tid & 63, w = tid >> 6;
  const int lh = lane & 15, lg = lane >> 4;

  __shared__ __align__(16) char smem[12480 + 65536];
  __shared__ float red[2][4][16];
  unsigned short* plds = (unsigned short*)smem;   // [12][520] bf16
  char* pwlds = smem + 12480;                     // [128][512] fp8, swizzled

  // pr B-frags (constant): B[k=c][col=h]
  short8v prf[4];
  #pragma unroll
  for (int ks = 0; ks < 4; ++ks) {
    short8v s = {0,0,0,0,0,0,0,0};
    if (lh < 12) {
      const float* p = pr_k + (size_t)lh*PAIRC + ks*32 + lg*8;
      #pragma unroll
      for (int j = 0; j < 8; ++j) s[j] = (short)f2bf(p[j] * RSQRT3);
    }
    prf[ks] = s;
  }

  // ---- phase 1: stream pw rows; prd MFMA (bf16) + fp8 tile writes ----
  f32x4 acc[8];
  #pragma unroll
  for (int f = 0; f < 8; ++f) { f32x4 z = {0.f,0.f,0.f,0.f}; acc[f] = z; }

  const int mbase = w * 128;
  const float* rowp = pw + (size_t)n*LQ*PAIRC + (size_t)(mbase + lh)*PAIRC;

  float4 cur[8], nxt[8];
  #pragma unroll
  for (int q = 0; q < 8; ++q)
    cur[q] = *(const float4*)(rowp + (q>>1)*32 + lg*8 + (q&1)*4);
  #pragma unroll
  for (int f = 0; f < 8; ++f) {
    const int fn = (f < 7) ? f + 1 : 7;
    #pragma unroll
    for (int q = 0; q < 8; ++q)
      nxt[q] = *(const float4*)(rowp + (size_t)fn*16*PAIRC + (q>>1)*32 + lg*8 + (q&1)*4);
    const int m = mbase + f*16 + lh;
    const int mrow = m >> 3, mbyte = m & 7;
    #pragma unroll
    for (int ks = 0; ks < 4; ++ks) {
      float4 A = cur[ks*2], B = cur[ks*2+1];
      short8v a = pack8t(A, B);
      acc[f] = __builtin_amdgcn_mfma_f32_16x16x32_bf16(a, prf[ks], acc[f], 0, 0, 0);
      int u0 = __builtin_amdgcn_cvt_pk_fp8_f32(A.x, A.y, 0, false);
      u0 = __builtin_amdgcn_cvt_pk_fp8_f32(A.z, A.w, u0, true);
      int u1 = __builtin_amdgcn_cvt_pk_fp8_f32(B.x, B.y, 0, false);
      u1 = __builtin_amdgcn_cvt_pk_fp8_f32(B.z, B.w, u1, true);
      #pragma unroll
      for (int j = 0; j < 8; ++j) {
        const int c = ks*32 + lg*8 + j;
        const int slot = mrow ^ ((c & 7) << 3) ^ ((c >> 3) & 7);
        pwlds[(size_t)c*512 + (slot << 3) + mbyte] =
            (char)(((j < 4 ? u0 : u1) >> (8*(j & 3))) & 0xff);
      }
    }
    #pragma unroll
    for (int q = 0; q < 8; ++q) cur[q] = nxt[q];
  }

  // pre -> registers (after phase 1: keeps streaming-loop pressure low)
  float4 pre4[8];
  #pragma unroll
  for (int f = 0; f < 8; ++f) {
    if (lh < 12)
      pre4[f] = *(const float4*)(pre_w + ((size_t)lh*LQ + n)*LQ + mbase + f*16 + lg*4);
    else { float4 z = {0.f,0.f,0.f,0.f}; pre4[f] = z; }
  }

  // ---- logits + block softmax (head = lh, m = mbase + f*16 + lg*4 + r) ----
  float mx = -INFINITY;
  #pragma unroll
  for (int f = 0; f < 8; ++f) {
    #pragma unroll
    for (int r = 0; r < 4; ++r) {
      float p = (r == 0) ? pre4[f].x : (r == 1) ? pre4[f].y : (r == 2) ? pre4[f].z : pre4[f].w;
      float v = acc[f][r] + p;
      acc[f][r] = v;
      mx = fmaxf(mx, v);
    }
  }
  mx = fmaxf(mx, __shfl_xor(mx, 16));
  mx = fmaxf(mx, __shfl_xor(mx, 32));
  if (lane < 16) red[0][w][lane] = mx;
  __syncthreads();   // B2
  float M = fmaxf(fmaxf(red[0][0][lh], red[0][1][lh]),
                  fmaxf(red[0][2][lh], red[0][3][lh]));
  float sm = 0.f;
  #pragma unroll
  for (int f = 0; f < 8; ++f) {
    #pragma unroll
    for (int r = 0; r < 4; ++r) {
      float e = __expf(acc[f][r] - M);
      acc[f][r] = e;
      sm += e;
    }
  }
  sm += __shfl_xor(sm, 16);
  sm += __shfl_xor(sm, 32);
  if (lane < 16) red[1][w][lane] = sm;
  __syncthreads();   // B3
  float S = red[1][0][lh] + red[1][1][lh] + red[1][2][lh] + red[1][3][lh];
  float rinv = 1.f / S;
  if (lh < 12) {
    #pragma unroll
    for (int f = 0; f < 8; ++f) {
      #pragma unroll
      for (int r = 0; r < 4; ++r) {
        int m = mbase + f*16 + lg*4 + r;
        plds[lh*PRE_STR + m] = f2bf(acc[f][r] * rinv);
      }
    }
  }
  __syncthreads();   // B4: plds + pwlds ready

  // attn global write (bf16) for K5
  #pragma unroll
  for (int i = 0; i < 3; ++i) {
    int c8 = tid + 256*i;                 // 12 heads x 64 chunks
    int h = c8 >> 6, m = (c8 & 63) * 8;
    short8v v = *(const short8v*)(plds + h*PRE_STR + m);
    *(short8v*)(attn_w + ((size_t)h*LQ + n)*LQ + m) = v;
  }

  // ---- phase 2: PV via fp8 MFMA from the swizzled tile ----
  long a_r[16];
  #pragma unroll
  for (int ks = 0; ks < 16; ++ks) {
    const unsigned short* ap = plds + lh*PRE_STR + ks*32 + lg*8;
    float f0 = bf2f(ap[0]), f1 = bf2f(ap[1]), f2 = bf2f(ap[2]), f3 = bf2f(ap[3]);
    float f4 = bf2f(ap[4]), f5 = bf2f(ap[5]), f6 = bf2f(ap[6]), f7 = bf2f(ap[7]);
    int u0 = __builtin_amdgcn_cvt_pk_fp8_f32(f0, f1, 0, false);
    u0 = __builtin_amdgcn_cvt_pk_fp8_f32(f2, f3, u0, true);
    int u1 = __builtin_amdgcn_cvt_pk_fp8_f32(f4, f5, 0, false);
    u1 = __builtin_amdgcn_cvt_pk_fp8_f32(f6, f7, u1, true);
    a_r[ks] = (long)((((unsigned long long)(unsigned)u1) << 32) | (unsigned)u0);
  }
  #pragma unroll
  for (int cb = 0; cb < 2; ++cb) {
    const int c = w*32 + cb*16 + lh;
    f32x4 o = {0.f,0.f,0.f,0.f};
    #pragma unroll 4
    for (int ks = 0; ks < 16; ++ks) {
      const int slot = (ks*4 + lg) ^ ((c & 7) << 3) ^ ((c >> 3) & 7);
      long b = *(const long*)(pwlds + (size_t)c*512 + (slot << 3));
      o = __builtin_amdgcn_mfma_f32_16x16x32_fp8_fp8(a_r[ks], b, o, 0, 0, 0);
    }
    #pragma unroll
    for (int r = 0; r < 4; ++r) {
      int h = lg*4 + r;
      if (h < 12)
        rh_w[(size_t)n*2112 + h*176 + 16 + c] = f2bf(o[r]);
    }
  }
}

// ---------------------------------------------------------------------------
// K5: scaler + point PV from materialized attn, with fused point-output
// frame transform + norms via an LDS stage. (verified r8)
// ---------------------------------------------------------------------------
__global__ __launch_bounds__(256) void k5_svpv(
    const unsigned short* __restrict__ attn_w, const unsigned short* __restrict__ vf_w,
    const float* __restrict__ Rm, const float* __restrict__ tv,
    unsigned short* __restrict__ rh_w)
{
  const int n0 = blockIdx.x*64, h = blockIdx.y;
  const int tid = threadIdx.x, lane = tid & 63, w = tid >> 6;
  const int lh = lane & 15, lg = lane >> 4;
  const int nb = n0 + w*16;

  __shared__ float po_s[64][24];

  f32x4 acc[3];
  #pragma unroll
  for (int v = 0; v < 3; ++v) { f32x4 z = {0.f,0.f,0.f,0.f}; acc[v] = z; }

  #pragma unroll 4
  for (int ks = 0; ks < 16; ++ks) {
    short8v a = *(const short8v*)(attn_w + ((size_t)h*LQ + nb + lh)*LQ + ks*32 + lg*8);
    #pragma unroll
    for (int v = 0; v < 3; ++v) {
      short8v b = *(const short8v*)(vf_w + ((size_t)h*48 + v*16 + lh)*LQ + ks*32 + lg*8);
      acc[v] = __builtin_amdgcn_mfma_f32_16x16x32_bf16(a, b, acc[v], 0, 0, 0);
    }
  }
  #pragma unroll
  for (int v = 0; v < 3; ++v) {
    #pragma unroll
    for (int r = 0; r < 4; ++r) {
      int col = v*16 + lh;
      int nn = nb + lg*4 + r;
      float val = acc[v][r];
      if (col < 16)      rh_w[(size_t)nn*2112 + h*176 + col] = f2bf(val);
      else if (col < 40) po_s[nn - n0][col - 16] = val;
    }
  }
  __syncthreads();
  // point transform: subtract t, rotate by R^T, norms
  #pragma unroll
  for (int it = 0; it < 2; ++it) {
    int slot = it*256 + tid;          // 0..511
    int nl = slot >> 3, p = slot & 7;
    int nn = n0 + nl;
    float v0 = po_s[nl][p*3+0] - tv[(size_t)nn*3+0];
    float v1 = po_s[nl][p*3+1] - tv[(size_t)nn*3+1];
    float v2 = po_s[nl][p*3+2] - tv[(size_t)nn*3+2];
    const float* R_ = Rm + (size_t)nn*9;
    float f0 = v0*R_[0] + v1*R_[3] + v2*R_[6];
    float f1 = v0*R_[1] + v1*R_[4] + v2*R_[7];
    float f2 = v0*R_[2] + v1*R_[5] + v2*R_[8];
    unsigned short* d = rh_w + (size_t)nn*2112 + h*176;
    d[144 + p*3 + 0] = f2bf(f0);
    d[144 + p*3 + 1] = f2bf(f1);
    d[144 + p*3 + 2] = f2bf(f2);
    d[168 + p] = f2bf(sqrtf(f0*f0 + f1*f1 + f2*f2 + 1e-12f));
  }
}

// ---------------------------------------------------------------------------
// K3packB: out_k [2112][384] f32 -> bh_t [384][2112] bf16 (LDS tile transpose)
// ---------------------------------------------------------------------------
__global__ __launch_bounds__(256) void k3_packB(
    const float* __restrict__ out_k, unsigned short* __restrict__ bh_t)
{
  const int i0 = blockIdx.x*64, o0 = blockIdx.y*64;
  const int tid = threadIdx.x;
  __shared__ float t[64][65];
  #pragma unroll
  for (int e = 0; e < 16; ++e) {
    int idx = e*256 + tid;
    int i = idx >> 6, o = idx & 63;
    t[i][o] = out_k[(size_t)(i0 + i)*384 + o0 + o];
  }
  __syncthreads();
  #pragma unroll
  for (int e = 0; e < 16; ++e) {
    int idx = e*256 + tid;
    int o = idx >> 6, i = idx & 63;
    bh_t[(size_t)(o0 + o)*2112 + i0 + i] = f2bf(t[i][o]);
  }
}

// ---------------------------------------------------------------------------
// K3: out = res(512x2112, bf16) @ out_k^T(384x2112, bf16) via MFMA, split-K 6.
// ---------------------------------------------------------------------------
__global__ __launch_bounds__(256) void k3_mfma(
    const unsigned short* __restrict__ rh, const unsigned short* __restrict__ bh_t,
    float* __restrict__ part)
{
  const int l0 = blockIdx.x*64, o0 = blockIdx.y*64, z = blockIdx.z;
  const int tid = threadIdx.x, lane = tid & 63, w = tid >> 6;
  const int lh = lane & 15, lg = lane >> 4;
  const int wr = w >> 1, wc = w & 1;

  f32x4 acc[2][2];
  #pragma unroll
  for (int t = 0; t < 2; ++t)
    #pragma unroll
    for (int u = 0; u < 2; ++u) { f32x4 zz = {0.f,0.f,0.f,0.f}; acc[t][u] = zz; }

  const int k0 = z*352;
  #pragma unroll 2
  for (int ks = 0; ks < 11; ++ks) {
    const int koff = k0 + ks*32 + lg*8;
    short8v at[2], bt[2];
    #pragma unroll
    for (int t = 0; t < 2; ++t)
      at[t] = *(const short8v*)(rh + (size_t)(l0 + wr*32 + t*16 + lh)*2112 + koff);
    #pragma unroll
    for (int u = 0; u < 2; ++u)
      bt[u] = *(const short8v*)(bh_t + (size_t)(o0 + wc*32 + u*16 + lh)*2112 + koff);
    #pragma unroll
    for (int t = 0; t < 2; ++t)
      #pragma unroll
      for (int u = 0; u < 2; ++u)
        acc[t][u] = __builtin_amdgcn_mfma_f32_16x16x32_bf16(at[t], bt[u], acc[t][u], 0, 0, 0);
  }
  #pragma unroll
  for (int t = 0; t < 2; ++t)
    #pragma unroll
    for (int u = 0; u < 2; ++u)
      #pragma unroll
      for (int r = 0; r < 4; ++r) {
        int l = l0 + wr*32 + t*16 + lg*4 + r;
        int o = o0 + wc*32 + u*16 + lh;
        part[((size_t)z*LQ + l)*384 + o] = acc[t][u][r];
      }
}

__global__ __launch_bounds__(256) void k3_red(
    const float* __restrict__ part, const float* __restrict__ bias, float* __restrict__ out)
{
  int e4 = blockIdx.x*256 + threadIdx.x;   // 0..49151
  const float4* P4 = (const float4*)part;
  float4 s = {0,0,0,0};
  #pragma unroll
  for (int z = 0; z < 6; ++z) {
    float4 v = P4[(size_t)z*49152 + e4];
    s.x += v.x; s.y += v.y; s.z += v.z; s.w += v.w;
  }
  float4 b = ((const float4*)bias)[e4 % 96];
  s.x += b.x; s.y += b.y; s.z += b.z; s.w += b.w;
  ((float4*)out)[e4] = s;
}

// ---------------------------------------------------------------------------
extern "C" void kernel_launch(void* const* d_in, const int* in_sizes, int n_in,
                              void* d_out, int out_size, void* d_ws, size_t ws_size,
                              hipStream_t stream) {
  (void)in_sizes; (void)n_in; (void)out_size; (void)ws_size;
  const float* node  = (const float*)d_in[0];
  const float* Rm    = (const float*)d_in[1];
  const float* tv    = (const float*)d_in[2];
  const float* pairw = (const float*)d_in[3];
  const float* sq_k  = (const float*)d_in[4];
  const float* sk_k  = (const float*)d_in[5];
  const float* sv_k  = (const float*)d_in[6];
  const float* pq_k  = (const float*)d_in[7];
  const float* pk_k  = (const float*)d_in[8];
  const float* pv_k  = (const float*)d_in[9];
  const float* pr_k  = (const float*)d_in[10];
  const float* out_k = (const float*)d_in[11];
  const float* out_b = (const float*)d_in[12];
  const float* pwgt  = (const float*)d_in[13];

  float* ws = (float*)d_ws;
  // pre_w spans [0, 3145728); k1-stage scratch + k3 partials alias inside it.
  float* pre_w = ws + 0;                                   // 3145728 f
  unsigned short* nh   = (unsigned short*)(ws + 0);
  unsigned short* nl   = (unsigned short*)(ws + 98304);
  unsigned short* Wh   = (unsigned short*)(ws + 196608);
  unsigned short* Wl   = (unsigned short*)(ws + 417792);
  float* proj = ws + 638976;                               // 2 x 589824 f
  float* part_w = ws + 0;                                  // 1179648 f (alias pre)
  unsigned short* qfh = (unsigned short*)(ws + 3145728);
  unsigned short* qfl = (unsigned short*)(ws + 3244032);
  unsigned short* kfh = (unsigned short*)(ws + 3342336);
  unsigned short* kfl = (unsigned short*)(ws + 3440640);
  unsigned short* vf_w = (unsigned short*)(ws + 3538944);  // 294912 sh
  unsigned short* attn_w = (unsigned short*)(ws + 3686400);// 3145728 sh
  unsigned short* rh_w = (unsigned short*)(ws + 5259264);  // 1081344 sh
  unsigned short* bh_t = (unsigned short*)(ws + 5947392);  // 811008 sh

  k0_pack<<<dim3(2496,1,1), 256, 0, stream>>>(node, sq_k, sk_k, sv_k, pq_k, pk_k, pv_k,
                                              nh, nl, Wh, Wl);
  k1_mfma<<<dim3(32,12,2), 64, 0, stream>>>(nh, nl, Wh, Wl, proj);
  k1b_feat<<<dim3(24,1,1), 256, 0, stream>>>(proj, Rm, tv, pwgt,
                                             qfh, qfl, kfh, kfl, vf_w);
  k_qk<<<dim3(8,8,12), 256, 0, stream>>>(qfh, qfl, kfh, kfl, pre_w);
  k2j_attn<<<dim3(512,1,1), 256, 0, stream>>>(pairw, pr_k, pre_w, attn_w, rh_w);
  k5_svpv<<<dim3(8,12,1), 256, 0, stream>>>(attn_w, vf_w, Rm, tv, rh_w);
  k3_packB<<<dim3(33,6,1), 256, 0, stream>>>(out_k, bh_t);
  k3_mfma<<<dim3(8,6,6), 256, 0, stream>>>(rh_w, bh_t, part_w);
  k3_red<<<dim3(192,1,1), 256, 0, stream>>>(part_w, out_b, (float*)d_out);
}